// Round 1
// baseline (5978.461 us; speedup 1.0000x reference)
//
#include <hip/hip_runtime.h>
#include <math.h>

#define NNODES 100000
#define NEDGES 1600000
#define DF 128
#define ED 16

// ---------------- transpose edge-MLP layer-1 weights: t[j*16+k] = w[k*128+j]
__global__ void k_transpose(const float* __restrict__ wa, const float* __restrict__ wb,
                            float* __restrict__ ta, float* __restrict__ tb) {
    int t = blockIdx.x * blockDim.x + threadIdx.x;
    if (t >= 2 * 2048) return;
    const float* src = (t < 2048) ? wa : wb;
    float*       dst = (t < 2048) ? ta : tb;
    int i = t & 2047;
    int j = i >> 4, k = i & 15;
    dst[i] = src[k * DF + j];
}

// ---------------- deg init (self-loop weight 1)
__global__ void k_deg_init(float* __restrict__ d1, float* __restrict__ d2) {
    int i = blockIdx.x * blockDim.x + threadIdx.x;
    if (i < NNODES) { d1[i] = 1.f; d2[i] = 1.f; }
}

// ---------------- edge gates for BOTH layers + weighted-degree atomics
__global__ __launch_bounds__(256) void k_gates(
    const float* __restrict__ ea, const int* __restrict__ ei,
    const float* __restrict__ w1t1, const float* __restrict__ b11,
    const float* __restrict__ w21,  const float* __restrict__ b21,
    const float* __restrict__ w1t2, const float* __restrict__ b12,
    const float* __restrict__ w22,  const float* __restrict__ b22,
    float* __restrict__ g1, float* __restrict__ g2,
    float* __restrict__ deg1, float* __restrict__ deg2) {
    __shared__ __align__(16) float sw1[2048], sw1b[2048];
    __shared__ float sb1[128], sw2[128], sb1b[128], sw2b[128];
    int t = threadIdx.x;
    for (int i = t; i < 2048; i += 256) { sw1[i] = w1t1[i]; sw1b[i] = w1t2[i]; }
    if (t < 128) { sb1[t] = b11[t]; sw2[t] = w21[t]; sb1b[t] = b12[t]; sw2b[t] = w22[t]; }
    __syncthreads();

    int e = blockIdx.x * 256 + t;
    if (e >= NEDGES) return;

    float a[16];
    const float4* ea4 = (const float4*)(ea + (size_t)e * ED);
#pragma unroll
    for (int q = 0; q < 4; q++) {
        float4 v = ea4[q];
        a[q*4+0] = v.x; a[q*4+1] = v.y; a[q*4+2] = v.z; a[q*4+3] = v.w;
    }

    float z1 = b21[0], z2 = b22[0];
#pragma unroll 4
    for (int j = 0; j < 128; j++) {
        const float4* wa = (const float4*)(sw1  + j * 16);
        const float4* wb = (const float4*)(sw1b + j * 16);
        float4 p0 = wa[0], p1 = wa[1], p2 = wa[2], p3 = wa[3];
        float h1 = sb1[j]
            + a[0]*p0.x + a[1]*p0.y + a[2]*p0.z + a[3]*p0.w
            + a[4]*p1.x + a[5]*p1.y + a[6]*p1.z + a[7]*p1.w
            + a[8]*p2.x + a[9]*p2.y + a[10]*p2.z + a[11]*p2.w
            + a[12]*p3.x + a[13]*p3.y + a[14]*p3.z + a[15]*p3.w;
        float4 q0 = wb[0], q1 = wb[1], q2 = wb[2], q3 = wb[3];
        float h2 = sb1b[j]
            + a[0]*q0.x + a[1]*q0.y + a[2]*q0.z + a[3]*q0.w
            + a[4]*q1.x + a[5]*q1.y + a[6]*q1.z + a[7]*q1.w
            + a[8]*q2.x + a[9]*q2.y + a[10]*q2.z + a[11]*q2.w
            + a[12]*q3.x + a[13]*q3.y + a[14]*q3.z + a[15]*q3.w;
        z1 += fmaxf(h1, 0.f) * sw2[j];
        z2 += fmaxf(h2, 0.f) * sw2b[j];
    }
    float ga = 1.f / (1.f + expf(-z1));
    float gb = 1.f / (1.f + expf(-z2));
    g1[e] = ga; g2[e] = gb;
    int c = ei[NEDGES + e];
    atomicAdd(&deg1[c], ga);
    atomicAdd(&deg2[c], gb);
}

// ---------------- deg -> rsqrt(deg) in place (deg >= 1 always)
__global__ void k_rsqrt(float* __restrict__ d1, float* __restrict__ d2) {
    int i = blockIdx.x * blockDim.x + threadIdx.x;
    if (i < NNODES) { d1[i] = rsqrtf(d1[i]); d2[i] = rsqrtf(d2[i]); }
}

// ---------------- fp32 GEMM: Y[M,128] = act(X)[M,128] @ W[128,128]
// 64-row tile, K split in two 64-chunks to stay under 64KB LDS.
template <int RELU>
__global__ __launch_bounds__(256) void k_gemm(const float* __restrict__ X,
                                              const float* __restrict__ W,
                                              float* __restrict__ Y, int M) {
    __shared__ __align__(16) float sX[64 * 68];   // 64 rows x 64 k (+4 pad)
    __shared__ __align__(16) float sW[64 * 132];  // 64 k x 128 cols (+4 pad)
    int t = threadIdx.x;
    int row0 = blockIdx.x * 64;
    int tx = t & 15, ty = t >> 4;

    float acc[4][8];
#pragma unroll
    for (int i = 0; i < 4; i++)
#pragma unroll
        for (int j = 0; j < 8; j++) acc[i][j] = 0.f;

    for (int kt = 0; kt < 128; kt += 64) {
        // load X tile: 64 rows x 16 float4
        for (int i = t; i < 1024; i += 256) {
            int r = i >> 4, c4 = i & 15;
            float4 v = make_float4(0.f, 0.f, 0.f, 0.f);
            if (row0 + r < M) v = ((const float4*)X)[(size_t)(row0 + r) * 32 + (kt >> 2) + c4];
            if (RELU) {
                v.x = fmaxf(v.x, 0.f); v.y = fmaxf(v.y, 0.f);
                v.z = fmaxf(v.z, 0.f); v.w = fmaxf(v.w, 0.f);
            }
            ((float4*)(sX + r * 68))[c4] = v;
        }
        // load W tile: 64 k x 32 float4
        for (int i = t; i < 2048; i += 256) {
            int r = i >> 5, c4 = i & 31;
            float4 v = ((const float4*)W)[(size_t)(kt + r) * 32 + c4];
            ((float4*)(sW + r * 132))[c4] = v;
        }
        __syncthreads();
#pragma unroll 8
        for (int k = 0; k < 64; k++) {
            float xv[4];
#pragma unroll
            for (int i = 0; i < 4; i++) xv[i] = sX[(ty * 4 + i) * 68 + k];
            float4 wA = *(const float4*)(sW + k * 132 + tx * 4);
            float4 wB = *(const float4*)(sW + k * 132 + 64 + tx * 4);
#pragma unroll
            for (int i = 0; i < 4; i++) {
                acc[i][0] += xv[i] * wA.x; acc[i][1] += xv[i] * wA.y;
                acc[i][2] += xv[i] * wA.z; acc[i][3] += xv[i] * wA.w;
                acc[i][4] += xv[i] * wB.x; acc[i][5] += xv[i] * wB.y;
                acc[i][6] += xv[i] * wB.z; acc[i][7] += xv[i] * wB.w;
            }
        }
        __syncthreads();
    }
#pragma unroll
    for (int i = 0; i < 4; i++) {
        int r = row0 + ty * 4 + i;
        if (r < M) {
            float4 o1 = make_float4(acc[i][0], acc[i][1], acc[i][2], acc[i][3]);
            float4 o2 = make_float4(acc[i][4], acc[i][5], acc[i][6], acc[i][7]);
            *(float4*)(Y + (size_t)r * 128 + tx * 4) = o1;
            *(float4*)(Y + (size_t)r * 128 + 64 + tx * 4) = o2;
        }
    }
}

// ---------------- self-loop term: out[i][:] = dinv[i]^2 * h[i][:]
__global__ void k_selfloop(const float* __restrict__ h, const float* __restrict__ dinv,
                           float* __restrict__ out) {
    int i = blockIdx.x * blockDim.x + threadIdx.x;  // float4 index
    if (i >= NNODES * 32) return;
    int row = i >> 5;
    float d = dinv[row];
    float s = d * d;
    float4 v = ((const float4*)h)[i];
    v.x *= s; v.y *= s; v.z *= s; v.w *= s;
    ((float4*)out)[i] = v;
}

// ---------------- edge aggregation: out[col] += dinv[row]*g*dinv[col] * h[row]
__global__ __launch_bounds__(256) void k_agg(const int* __restrict__ ei,
                                             const float* __restrict__ g,
                                             const float* __restrict__ dinv,
                                             const float* __restrict__ h,
                                             float* out) {
    int t = blockIdx.x * 256 + threadIdx.x;
    int e = t >> 5, lane = t & 31;
    if (e >= NEDGES) return;
    int r = ei[e], c = ei[NEDGES + e];
    float w = dinv[r] * g[e] * dinv[c];
    float4 hv = ((const float4*)h)[(size_t)r * 32 + lane];
    float* o = out + (size_t)c * 128 + lane * 4;
    atomicAdd(o + 0, w * hv.x);
    atomicAdd(o + 1, w * hv.y);
    atomicAdd(o + 2, w * hv.z);
    atomicAdd(o + 3, w * hv.w);
}

extern "C" void kernel_launch(void* const* d_in, const int* in_sizes, int n_in,
                              void* d_out, int out_size, void* d_ws, size_t ws_size,
                              hipStream_t stream) {
    const float* x    = (const float*)d_in[0];
    const int*   ei   = (const int*)d_in[1];
    const float* ea   = (const float*)d_in[2];
    const float* W1   = (const float*)d_in[3];
    const float* m1w1 = (const float*)d_in[4];
    const float* m1b1 = (const float*)d_in[5];
    const float* m1w2 = (const float*)d_in[6];
    const float* m1b2 = (const float*)d_in[7];
    const float* W2   = (const float*)d_in[8];
    const float* m2w1 = (const float*)d_in[9];
    const float* m2b1 = (const float*)d_in[10];
    const float* m2w2 = (const float*)d_in[11];
    const float* m2b2 = (const float*)d_in[12];
    float* out = (float*)d_out;

    float* ws    = (float*)d_ws;
    float* g1    = ws;                      // E
    float* g2    = g1 + NEDGES;             // E
    float* deg1  = g2 + NEDGES;             // N
    float* deg2  = deg1 + NNODES;           // N
    float* hbuf  = deg2 + NNODES;           // N*128
    float* aggbf = hbuf + (size_t)NNODES * 128;   // N*128
    float* w1t1  = aggbf + (size_t)NNODES * 128;  // 2048
    float* w1t2  = w1t1 + 2048;                   // 2048

    k_transpose<<<16, 256, 0, stream>>>(m1w1, m2w1, w1t1, w1t2);
    k_deg_init<<<(NNODES + 255) / 256, 256, 0, stream>>>(deg1, deg2);
    k_gates<<<NEDGES / 256, 256, 0, stream>>>(ea, ei, w1t1, m1b1, m1w2, m1b2,
                                              w1t2, m2b1, m2w2, m2b2,
                                              g1, g2, deg1, deg2);
    k_rsqrt<<<(NNODES + 255) / 256, 256, 0, stream>>>(deg1, deg2);

    // layer 1
    k_gemm<0><<<(NNODES + 63) / 64, 256, 0, stream>>>(x, W1, hbuf, NNODES);
    k_selfloop<<<(NNODES * 32 + 255) / 256, 256, 0, stream>>>(hbuf, deg1, aggbf);
    k_agg<<<NEDGES * 32 / 256, 256, 0, stream>>>(ei, g1, deg1, hbuf, aggbf);

    // layer 2 (relu fused into GEMM load)
    k_gemm<1><<<(NNODES + 63) / 64, 256, 0, stream>>>(aggbf, W2, hbuf, NNODES);
    k_selfloop<<<(NNODES * 32 + 255) / 256, 256, 0, stream>>>(hbuf, deg2, out);
    k_agg<<<NEDGES * 32 / 256, 256, 0, stream>>>(ei, g2, deg2, hbuf, out);
}

// Round 2
// 956.427 us; speedup vs baseline: 6.2508x; 6.2508x over previous
//
#include <hip/hip_runtime.h>
#include <math.h>

#define NNODES 100000
#define NEDGES 1600000
#define DF 128
#define ED 16
#define NBLK_SCAN ((NNODES + 255) / 256)   // 391

// ---------------- transpose edge-MLP layer-1 weights: t[j*16+k] = w[k*128+j]
__global__ void k_transpose(const float* __restrict__ wa, const float* __restrict__ wb,
                            float* __restrict__ ta, float* __restrict__ tb) {
    int t = blockIdx.x * blockDim.x + threadIdx.x;
    if (t >= 2 * 2048) return;
    const float* src = (t < 2048) ? wa : wb;
    float*       dst = (t < 2048) ? ta : tb;
    int i = t & 2047;
    int j = i >> 4, k = i & 15;
    dst[i] = src[k * DF + j];
}

// ---------------- deg init (self-loop weight 1) + zero in-degree counters
__global__ void k_deg_init(float* __restrict__ d1, float* __restrict__ d2,
                           int* __restrict__ cnt) {
    int i = blockIdx.x * blockDim.x + threadIdx.x;
    if (i < NNODES) { d1[i] = 1.f; d2[i] = 1.f; cnt[i] = 0; }
}

// ---------------- edge gates for BOTH layers + weighted-degree + int histogram
__global__ __launch_bounds__(256) void k_gates(
    const float* __restrict__ ea, const int* __restrict__ ei,
    const float* __restrict__ w1t1, const float* __restrict__ b11,
    const float* __restrict__ w21,  const float* __restrict__ b21,
    const float* __restrict__ w1t2, const float* __restrict__ b12,
    const float* __restrict__ w22,  const float* __restrict__ b22,
    float* __restrict__ g1, float* __restrict__ g2,
    float* __restrict__ deg1, float* __restrict__ deg2,
    int* __restrict__ cnt) {
    __shared__ __align__(16) float sw1[2048], sw1b[2048];
    __shared__ float sb1[128], sw2[128], sb1b[128], sw2b[128];
    int t = threadIdx.x;
    for (int i = t; i < 2048; i += 256) { sw1[i] = w1t1[i]; sw1b[i] = w1t2[i]; }
    if (t < 128) { sb1[t] = b11[t]; sw2[t] = w21[t]; sb1b[t] = b12[t]; sw2b[t] = w22[t]; }
    __syncthreads();

    int e = blockIdx.x * 256 + t;
    if (e >= NEDGES) return;

    float a[16];
    const float4* ea4 = (const float4*)(ea + (size_t)e * ED);
#pragma unroll
    for (int q = 0; q < 4; q++) {
        float4 v = ea4[q];
        a[q*4+0] = v.x; a[q*4+1] = v.y; a[q*4+2] = v.z; a[q*4+3] = v.w;
    }

    float z1 = b21[0], z2 = b22[0];
#pragma unroll 4
    for (int j = 0; j < 128; j++) {
        const float4* wa = (const float4*)(sw1  + j * 16);
        const float4* wb = (const float4*)(sw1b + j * 16);
        float4 p0 = wa[0], p1 = wa[1], p2 = wa[2], p3 = wa[3];
        float h1 = sb1[j]
            + a[0]*p0.x + a[1]*p0.y + a[2]*p0.z + a[3]*p0.w
            + a[4]*p1.x + a[5]*p1.y + a[6]*p1.z + a[7]*p1.w
            + a[8]*p2.x + a[9]*p2.y + a[10]*p2.z + a[11]*p2.w
            + a[12]*p3.x + a[13]*p3.y + a[14]*p3.z + a[15]*p3.w;
        float4 q0 = wb[0], q1 = wb[1], q2 = wb[2], q3 = wb[3];
        float h2 = sb1b[j]
            + a[0]*q0.x + a[1]*q0.y + a[2]*q0.z + a[3]*q0.w
            + a[4]*q1.x + a[5]*q1.y + a[6]*q1.z + a[7]*q1.w
            + a[8]*q2.x + a[9]*q2.y + a[10]*q2.z + a[11]*q2.w
            + a[12]*q3.x + a[13]*q3.y + a[14]*q3.z + a[15]*q3.w;
        z1 += fmaxf(h1, 0.f) * sw2[j];
        z2 += fmaxf(h2, 0.f) * sw2b[j];
    }
    float ga = 1.f / (1.f + expf(-z1));
    float gb = 1.f / (1.f + expf(-z2));
    g1[e] = ga; g2[e] = gb;
    int c = ei[NEDGES + e];
    atomicAdd(&deg1[c], ga);
    atomicAdd(&deg2[c], gb);
    atomicAdd(&cnt[c], 1);
}

// ---------------- deg -> rsqrt(deg) in place (deg >= 1 always)
__global__ void k_rsqrt(float* __restrict__ d1, float* __restrict__ d2) {
    int i = blockIdx.x * blockDim.x + threadIdx.x;
    if (i < NNODES) { d1[i] = rsqrtf(d1[i]); d2[i] = rsqrtf(d2[i]); }
}

// ---------------- scan phase 1: per-256-block exclusive scan + block sums
__global__ __launch_bounds__(256) void k_scan1(const int* __restrict__ cnt,
                                               int* __restrict__ offs,
                                               int* __restrict__ partial) {
    __shared__ int s[256];
    int t = threadIdx.x;
    int gid = blockIdx.x * 256 + t;
    int own = (gid < NNODES) ? cnt[gid] : 0;
    s[t] = own;
    __syncthreads();
    for (int off = 1; off < 256; off <<= 1) {
        int v = (t >= off) ? s[t - off] : 0;
        __syncthreads();
        s[t] += v;
        __syncthreads();
    }
    if (gid < NNODES) offs[gid] = s[t] - own;   // exclusive
    if (t == 255) partial[blockIdx.x] = s[255];
}

// ---------------- scan phase 2: single block scans the block sums (exclusive)
__global__ __launch_bounds__(512) void k_scan2(int* __restrict__ partial) {
    __shared__ int s[512];
    int t = threadIdx.x;
    int own = (t < NBLK_SCAN) ? partial[t] : 0;
    s[t] = own;
    __syncthreads();
    for (int off = 1; off < 512; off <<= 1) {
        int v = (t >= off) ? s[t - off] : 0;
        __syncthreads();
        s[t] += v;
        __syncthreads();
    }
    if (t < NBLK_SCAN) partial[t] = s[t] - own;  // exclusive
}

// ---------------- scan phase 3: add block offsets; init cursor; offs[N]=E
__global__ void k_scan3(int* __restrict__ offs, const int* __restrict__ partial,
                        int* __restrict__ cur) {
    int gid = blockIdx.x * blockDim.x + threadIdx.x;
    if (gid < NNODES) {
        int v = offs[gid] + partial[gid >> 8];
        offs[gid] = v;
        cur[gid] = v;
    }
    if (gid == 0) offs[NNODES] = NEDGES;
}

// ---------------- scatter edges into CSR slots + precompute per-layer norms
__global__ __launch_bounds__(256) void k_scatter(
    const int* __restrict__ ei, const float* __restrict__ g1,
    const float* __restrict__ g2, const float* __restrict__ dinv1,
    const float* __restrict__ dinv2, int* __restrict__ cur,
    int* __restrict__ prow, float* __restrict__ wl1, float* __restrict__ wl2) {
    int e = blockIdx.x * 256 + threadIdx.x;
    if (e >= NEDGES) return;
    int r = ei[e], c = ei[NEDGES + e];
    int pos = atomicAdd(&cur[c], 1);
    prow[pos] = r;
    wl1[pos] = dinv1[r] * g1[e] * dinv1[c];
    wl2[pos] = dinv2[r] * g2[e] * dinv2[c];
}

// ---------------- fp32 GEMM: Y[M,128] = act(X)[M,128] @ W[128,128]
template <int RELU>
__global__ __launch_bounds__(256) void k_gemm(const float* __restrict__ X,
                                              const float* __restrict__ W,
                                              float* __restrict__ Y, int M) {
    __shared__ __align__(16) float sX[64 * 68];
    __shared__ __align__(16) float sW[64 * 132];
    int t = threadIdx.x;
    int row0 = blockIdx.x * 64;
    int tx = t & 15, ty = t >> 4;

    float acc[4][8];
#pragma unroll
    for (int i = 0; i < 4; i++)
#pragma unroll
        for (int j = 0; j < 8; j++) acc[i][j] = 0.f;

    for (int kt = 0; kt < 128; kt += 64) {
        for (int i = t; i < 1024; i += 256) {
            int r = i >> 4, c4 = i & 15;
            float4 v = make_float4(0.f, 0.f, 0.f, 0.f);
            if (row0 + r < M) v = ((const float4*)X)[(size_t)(row0 + r) * 32 + (kt >> 2) + c4];
            if (RELU) {
                v.x = fmaxf(v.x, 0.f); v.y = fmaxf(v.y, 0.f);
                v.z = fmaxf(v.z, 0.f); v.w = fmaxf(v.w, 0.f);
            }
            ((float4*)(sX + r * 68))[c4] = v;
        }
        for (int i = t; i < 2048; i += 256) {
            int r = i >> 5, c4 = i & 31;
            float4 v = ((const float4*)W)[(size_t)(kt + r) * 32 + c4];
            ((float4*)(sW + r * 132))[c4] = v;
        }
        __syncthreads();
#pragma unroll 8
        for (int k = 0; k < 64; k++) {
            float xv[4];
#pragma unroll
            for (int i = 0; i < 4; i++) xv[i] = sX[(ty * 4 + i) * 68 + k];
            float4 wA = *(const float4*)(sW + k * 132 + tx * 4);
            float4 wB = *(const float4*)(sW + k * 132 + 64 + tx * 4);
#pragma unroll
            for (int i = 0; i < 4; i++) {
                acc[i][0] += xv[i] * wA.x; acc[i][1] += xv[i] * wA.y;
                acc[i][2] += xv[i] * wA.z; acc[i][3] += xv[i] * wA.w;
                acc[i][4] += xv[i] * wB.x; acc[i][5] += xv[i] * wB.y;
                acc[i][6] += xv[i] * wB.z; acc[i][7] += xv[i] * wB.w;
            }
        }
        __syncthreads();
    }
#pragma unroll
    for (int i = 0; i < 4; i++) {
        int r = row0 + ty * 4 + i;
        if (r < M) {
            float4 o1 = make_float4(acc[i][0], acc[i][1], acc[i][2], acc[i][3]);
            float4 o2 = make_float4(acc[i][4], acc[i][5], acc[i][6], acc[i][7]);
            *(float4*)(Y + (size_t)r * 128 + tx * 4) = o1;
            *(float4*)(Y + (size_t)r * 128 + 64 + tx * 4) = o2;
        }
    }
}

// ---------------- CSR aggregation: one wave per node, register accumulation.
// out[i] = dinv[i]^2 * h[i] + sum_{e in CSR(i)} wl[e] * h[prow[e]]
__global__ __launch_bounds__(256) void k_aggcsr(
    const int* __restrict__ offs, const int* __restrict__ prow,
    const float* __restrict__ wl, const float* __restrict__ dinv,
    const float* __restrict__ h, float* __restrict__ out) {
    int node = blockIdx.x * 4 + (threadIdx.x >> 6);   // 4 waves/block, 1 node/wave
    if (node >= NNODES) return;
    int lane = threadIdx.x & 63;
    int beg = offs[node], end = offs[node + 1];
    float d = dinv[node];
    float2 hv = ((const float2*)h)[(size_t)node * 64 + lane];
    float2 acc;
    acc.x = d * d * hv.x;
    acc.y = d * d * hv.y;
    // software-pipelined edge loop (hide prow/wl -> gather dependency)
    int   r_n = 0; float w_n = 0.f;
    if (beg < end) { r_n = prow[beg]; w_n = wl[beg]; }
    for (int e = beg; e < end; e++) {
        int   r = r_n;
        float w = w_n;
        if (e + 1 < end) { r_n = prow[e + 1]; w_n = wl[e + 1]; }
        float2 v = ((const float2*)h)[(size_t)r * 64 + lane];
        acc.x += w * v.x;
        acc.y += w * v.y;
    }
    ((float2*)out)[(size_t)node * 64 + lane] = acc;
}

extern "C" void kernel_launch(void* const* d_in, const int* in_sizes, int n_in,
                              void* d_out, int out_size, void* d_ws, size_t ws_size,
                              hipStream_t stream) {
    const float* x    = (const float*)d_in[0];
    const int*   ei   = (const int*)d_in[1];
    const float* ea   = (const float*)d_in[2];
    const float* W1   = (const float*)d_in[3];
    const float* m1w1 = (const float*)d_in[4];
    const float* m1b1 = (const float*)d_in[5];
    const float* m1w2 = (const float*)d_in[6];
    const float* m1b2 = (const float*)d_in[7];
    const float* W2   = (const float*)d_in[8];
    const float* m2w1 = (const float*)d_in[9];
    const float* m2b1 = (const float*)d_in[10];
    const float* m2w2 = (const float*)d_in[11];
    const float* m2b2 = (const float*)d_in[12];
    float* out = (float*)d_out;

    float* ws    = (float*)d_ws;
    float* g1    = ws;                               // E
    float* g2    = g1 + NEDGES;                      // E
    float* deg1  = g2 + NEDGES;                      // N
    float* deg2  = deg1 + NNODES;                    // N
    float* hbuf  = deg2 + NNODES;                    // N*128
    float* aggbf = hbuf + (size_t)NNODES * 128;      // N*128
    float* w1t1  = aggbf + (size_t)NNODES * 128;     // 2048
    float* w1t2  = w1t1 + 2048;                      // 2048
    float* wl1   = w1t2 + 2048;                      // E
    float* wl2   = wl1 + NEDGES;                     // E
    int*   cnt   = (int*)(wl2 + NEDGES);             // N (also cursor)
    int*   offs  = cnt + NNODES;                     // N+1
    int*   part  = offs + NNODES + 1;                // 1024
    int*   prow  = part + 1024;                      // E

    k_transpose<<<16, 256, 0, stream>>>(m1w1, m2w1, w1t1, w1t2);
    k_deg_init<<<(NNODES + 255) / 256, 256, 0, stream>>>(deg1, deg2, cnt);
    k_gates<<<NEDGES / 256, 256, 0, stream>>>(ea, ei, w1t1, m1b1, m1w2, m1b2,
                                              w1t2, m2b1, m2w2, m2b2,
                                              g1, g2, deg1, deg2, cnt);
    k_rsqrt<<<(NNODES + 255) / 256, 256, 0, stream>>>(deg1, deg2);

    // CSR build (graph shared by both layers)
    k_scan1<<<NBLK_SCAN, 256, 0, stream>>>(cnt, offs, part);
    k_scan2<<<1, 512, 0, stream>>>(part);
    k_scan3<<<(NNODES + 255) / 256, 256, 0, stream>>>(offs, part, cnt);
    k_scatter<<<NEDGES / 256, 256, 0, stream>>>(ei, g1, g2, deg1, deg2,
                                                cnt, prow, wl1, wl2);

    // layer 1
    k_gemm<0><<<(NNODES + 63) / 64, 256, 0, stream>>>(x, W1, hbuf, NNODES);
    k_aggcsr<<<(NNODES + 3) / 4, 256, 0, stream>>>(offs, prow, wl1, deg1, hbuf, aggbf);

    // layer 2 (relu fused into GEMM load)
    k_gemm<1><<<(NNODES + 63) / 64, 256, 0, stream>>>(aggbf, W2, hbuf, NNODES);
    k_aggcsr<<<(NNODES + 3) / 4, 256, 0, stream>>>(offs, prow, wl2, deg2, hbuf, out);
}